// Round 4
// baseline (316.239 us; speedup 1.0000x reference)
//
#include <hip/hip_runtime.h>
#include <hip/hip_bf16.h>

#define EPSF 1e-8f
#define GAINF 0.014731391274719739f   // 1/sqrt(512*9)

typedef __attribute__((ext_vector_type(8))) __bf16 bf16x8;
typedef __attribute__((ext_vector_type(16))) float f32x16;

// async 16B global->LDS DMA; HW dest = wave-uniform base + lane*16
#define GLOAD_LDS16(gp, lp) __builtin_amdgcn_global_load_lds( \
    (const __attribute__((address_space(1))) unsigned int*)(gp), \
    (__attribute__((address_space(3))) unsigned int*)(lp), 16, 0, 0)

static __device__ __forceinline__ unsigned pkbf(float a, float b) {
  unsigned ua = __bfloat16_as_ushort(__float2bfloat16(a));
  unsigned ub = __bfloat16_as_ushort(__float2bfloat16(b));
  return ua | (ub << 16);
}

// ---------------- K1: pack_x (+border) and prep_w ----------------------------
// xs:  [b][cb16][site1156][32ch] bf16 ; wbf: [t9][cb16][o512][32ch] bf16
__global__ void k_prep(const float* __restrict__ x, const float* __restrict__ style,
                       const float* __restrict__ w, float* __restrict__ S,
                       __hip_bfloat16* __restrict__ wbf, __hip_bfloat16* __restrict__ xs) {
  int blk = blockIdx.x, tid = threadIdx.x;
  if (blk < 1024) {
    // pack: block = (b, cb, quarter): 32ch x 256px, contiguous 1KB-run reads
    __shared__ float lt[256 * 33];
    int b = blk >> 6, cb = (blk >> 2) & 15, q = blk & 3;
    int c = tid >> 3, i8 = tid & 7;
    float st = style[b * 512 + cb * 32 + c];
    const float4* xp = reinterpret_cast<const float4*>(
        x + ((size_t)(b * 512 + cb * 32 + c) * 1024 + q * 256 + i8 * 32));
    float4 v[8];
#pragma unroll
    for (int j = 0; j < 8; ++j) v[j] = xp[j];
    int swz = (c + 4 * i8) & 31;  // 2-way max on store (free)
#pragma unroll
    for (int j = 0; j < 8; ++j) {
      int p = i8 * 32 + j * 4;
      lt[(p + 0) * 33 + swz] = v[j].x * st;
      lt[(p + 1) * 33 + swz] = v[j].y * st;
      lt[(p + 2) * 33 + swz] = v[j].z * st;
      lt[(p + 3) * 33 + swz] = v[j].w * st;
    }
    __syncthreads();
    int p = tid;                       // px-local 0..255
    int pq = q * 256 + p;
    int y = pq >> 5, xx = pq & 31;
    int site = (y + 1) * 34 + (xx + 1);
    __hip_bfloat16* dst = xs + ((size_t)(b * 16 + cb) * 1156 + site) * 32;
    int rs = 4 * (p >> 5);
#pragma unroll
    for (int k = 0; k < 4; ++k) {
      uint4 ov;
      ov.x = pkbf(lt[p * 33 + ((8 * k + 0 + rs) & 31)], lt[p * 33 + ((8 * k + 1 + rs) & 31)]);
      ov.y = pkbf(lt[p * 33 + ((8 * k + 2 + rs) & 31)], lt[p * 33 + ((8 * k + 3 + rs) & 31)]);
      ov.z = pkbf(lt[p * 33 + ((8 * k + 4 + rs) & 31)], lt[p * 33 + ((8 * k + 5 + rs) & 31)]);
      ov.w = pkbf(lt[p * 33 + ((8 * k + 6 + rs) & 31)], lt[p * 33 + ((8 * k + 7 + rs) & 31)]);
      reinterpret_cast<uint4*>(dst)[k] = ov;
    }
    // border zero: 33 of 132 sites per quarter (disjoint from interior writes)
    if (tid < 33) {
      int sbi = q * 33 + tid;
      if (sbi < 132) {
        int yp, xp2;
        if (sbi < 34) { yp = 0; xp2 = sbi; }
        else if (sbi < 68) { yp = 33; xp2 = sbi - 34; }
        else { int t2 = sbi - 68; yp = 1 + (t2 >> 1); xp2 = (t2 & 1) * 33; }
        uint4 z = {0u, 0u, 0u, 0u};
        uint4* zp = reinterpret_cast<uint4*>(
            xs + ((size_t)(b * 16 + cb) * 1156 + yp * 34 + xp2) * 32);
#pragma unroll
        for (int k = 0; k < 4; ++k) zp[k] = z;
      }
    }
  } else {
    // weight -> bf16 [t][cb][o][32] + S[o,i] = sum_t w^2
    int idx = (blk - 1024) * 256 + tid;  // o*512 + i, 262144 total
    int o = idx >> 9, i = idx & 511;
    const float* p = w + (size_t)idx * 9;
    float s = 0.f;
#pragma unroll
    for (int t = 0; t < 9; ++t) {
      float v = p[t];
      s += v * v;
      wbf[(size_t)(t * 16 + (i >> 5)) * 16384 + o * 32 + (i & 31)] = __float2bfloat16(v);
    }
    S[idx] = s;
  }
}

// ---------------- K2: esc[b,o] = GAIN * rsqrt(GAIN^2 * sum_i style^2 S + eps)
__global__ void k_sigma(const float* __restrict__ style, const float* __restrict__ S,
                        float* __restrict__ esc) {
  __shared__ float s2[8192];
  __shared__ float red[4][16];
  int tid = threadIdx.x, o = blockIdx.x;
  for (int idx = tid; idx < 8192; idx += 256) {
    float v = style[idx];
    s2[idx] = v * v;
  }
  __syncthreads();
  float acc[16];
#pragma unroll
  for (int b = 0; b < 16; ++b) acc[b] = 0.f;
  for (int i = tid; i < 512; i += 256) {
    float s = S[o * 512 + i];
#pragma unroll
    for (int b = 0; b < 16; ++b) acc[b] += s2[b * 512 + i] * s;
  }
#pragma unroll
  for (int b = 0; b < 16; ++b)
#pragma unroll
    for (int off = 32; off; off >>= 1) acc[b] += __shfl_down(acc[b], off);
  int lane = tid & 63, wv = tid >> 6;
  if (lane == 0)
#pragma unroll
    for (int b = 0; b < 16; ++b) red[wv][b] = acc[b];
  __syncthreads();
  if (tid < 16) {
    float s = red[0][tid] + red[1][tid] + red[2][tid] + red[3][tid];
    esc[tid * 512 + o] = GAINF * rsqrtf(s * (GAINF * GAINF) + EPSF);
  }
}

// ---------------- K3: implicit-GEMM conv, barrier-free single-wave pipeline --
// 512 blocks x 64 thr. Wave tile 128o x 128px (acc 4x4). B via async-DMA'd LDS
// (double buffer, fine-grained vmcnt -- no __syncthreads). A streamed from L1/L2.
__global__ __launch_bounds__(64, 1) void k_conv(
    const __hip_bfloat16* __restrict__ wbf, const __hip_bfloat16* __restrict__ xs,
    const float* __restrict__ esc, float* __restrict__ out) {
  __shared__ __hip_bfloat16 ldsB[2 * 6528];  // 2 bufs x 204 sites x 32 ch
  int g = blockIdx.x;
  int xcd = g & 7, sb = g >> 3;
  int m = sb >> 4;                 // same-m runs of 16: co-resident blocks share A in L1
  int n = xcd * 16 + (sb & 15);    // n-pinned: each XCD owns 2 images of xs
  int b = n >> 3, nt = n & 7;
  int row0 = nt * 4;               // padded-row base of the 6-row window
  int lane = threadIdx.x;
  int l31 = lane & 31, lhi = lane >> 5;

  // 816 16B chunks (204 sites x 4); XOR bank-swizzle applied on global side
  int roff[13];
#pragma unroll
  for (int j = 0; j < 13; ++j) {
    int idx = lane + j * 64;
    int site = idx >> 2, q0 = idx & 3;
    int qs = q0 ^ ((site >> 1) & 3);
    roff[j] = site * 32 + qs * 8;
  }
  const size_t slab = ((size_t)(b * 16) * 1156 + row0 * 34) * 32;

#define STAGE(cbv) do { \
    const __hip_bfloat16* _g = xs + slab + (size_t)(cbv) * (1156 * 32); \
    __hip_bfloat16* _l = ldsB + ((cbv) & 1) * 6528 + lane * 8; \
    _Pragma("unroll") \
    for (int _j = 0; _j < 12; ++_j) GLOAD_LDS16(_g + roff[_j], _l + _j * 512); \
    if (lane < 48) GLOAD_LDS16(_g + roff[12], _l + 12 * 512); \
  } while (0)

  const __hip_bfloat16* wlane = wbf + (m * 128 + l31) * 32 + lhi * 8;
#define LOADA(dst, t_, cb_) do { \
    const __hip_bfloat16* _p = wlane + (size_t)((t_) * 16 + (cb_)) * 16384; \
    _Pragma("unroll") \
    for (int _ms = 0; _ms < 4; ++_ms) { \
      dst[0][_ms] = *reinterpret_cast<const bf16x8*>(_p + _ms * 1024); \
      dst[1][_ms] = *reinterpret_cast<const bf16x8*>(_p + _ms * 1024 + 16); \
    } \
  } while (0)

  f32x16 acc[4][4];
#pragma unroll
  for (int i = 0; i < 4; ++i)
#pragma unroll
    for (int j = 0; j < 4; ++j)
#pragma unroll
      for (int e = 0; e < 16; ++e) acc[i][j][e] = 0.f;

  bf16x8 aC[2][4], aN[2][4];  // [k2][ms]
  STAGE(0);                   // 13 DMA
  LOADA(aC, 0, 0);            // 8 loads

  for (int cb = 0; cb < 16; ++cb) {
    if (cb < 15) {
      STAGE(cb + 1);  // 13 DMA into the other buffer, stays in flight all cb
      // wait for STAGE(cb): newest 21 = STAGE(cb+1)(13) + A(cb,t0)(8) stay outstanding
      asm volatile("s_waitcnt vmcnt(21)" ::: "memory");
    } else {
      asm volatile("s_waitcnt vmcnt(8)" ::: "memory");
    }
    const __hip_bfloat16* B = ldsB + (cb & 1) * 6528;
#pragma unroll
    for (int t = 0; t < 9; ++t) {
      const int dy = t / 3, dx = t - dy * 3;
      if (cb < 15 || t < 8) {  // prefetch next tap's A: 32-MFMA (~256cyc) distance
        int tn = (t == 8) ? 0 : t + 1;
        int cbn = (t == 8) ? cb + 1 : cb;
        LOADA(aN, tn, cbn);
      }
#pragma unroll
      for (int k2 = 0; k2 < 2; ++k2) {
        int ko = (k2 << 1) | lhi;
        bf16x8 bfr[4];
#pragma unroll
        for (int ns = 0; ns < 4; ++ns) {
          int s = (ns + dy) * 34 + l31 + dx;
          bfr[ns] = *reinterpret_cast<const bf16x8*>(&B[(s * 4 + (ko ^ ((s >> 1) & 3))) * 8]);
        }
#pragma unroll
        for (int ns = 0; ns < 4; ++ns)
#pragma unroll
          for (int ms = 0; ms < 4; ++ms)
            acc[ms][ns] = __builtin_amdgcn_mfma_f32_32x32x16_bf16(aC[k2][ms], bfr[ns],
                                                                  acc[ms][ns], 0, 0, 0);
      }
#pragma unroll
      for (int k2 = 0; k2 < 2; ++k2)
#pragma unroll
        for (int ms = 0; ms < 4; ++ms)
          aC[k2][ms] = aN[k2][ms];
    }
  }
  // epilogue: C/D layout col=lane&31, row=(reg&3)+8*(reg>>2)+4*(lane>>5)
  int pxb = nt * 128 + l31;
#pragma unroll
  for (int ms = 0; ms < 4; ++ms)
#pragma unroll
    for (int reg = 0; reg < 16; ++reg) {
      int o = m * 128 + ms * 32 + (reg & 3) + ((reg >> 2) << 3) + (lhi << 2);
      float e = esc[(b << 9) + o];
      float* op = out + ((size_t)((b << 9) + o) << 10) + pxb;
#pragma unroll
      for (int ns = 0; ns < 4; ++ns)
        op[ns * 32] = acc[ms][ns][reg] * e;
    }
#undef STAGE
#undef LOADA
}

extern "C" void kernel_launch(void* const* d_in, const int* in_sizes, int n_in,
                              void* d_out, int out_size, void* d_ws, size_t ws_size,
                              hipStream_t stream) {
  const float* x = (const float*)d_in[0];      // [16,512,32,32]
  const float* style = (const float*)d_in[1];  // [16,512]
  const float* w = (const float*)d_in[2];      // [512,512,3,3]
  float* out = (float*)d_out;                  // [16,512,32,32]
  char* ws = (char*)d_ws;
  __hip_bfloat16* wbf = (__hip_bfloat16*)(ws);            // 4,718,592 B
  __hip_bfloat16* xs  = (__hip_bfloat16*)(ws + 4718592);  // 18,939,904 B
  float* S   = (float*)(ws + 23658496);                   // 1,048,576 B
  float* esc = (float*)(ws + 24707072);                   // 32,768 B

  hipLaunchKernelGGL(k_prep, dim3(2048), dim3(256), 0, stream, x, style, w, S, wbf, xs);
  hipLaunchKernelGGL(k_sigma, dim3(512), dim3(256), 0, stream, style, S, esc);
  hipLaunchKernelGGL(k_conv, dim3(512), dim3(64), 0, stream, wbf, xs, esc, out);
}

// Round 5
// 189.213 us; speedup vs baseline: 1.6713x; 1.6713x over previous
//
#include <hip/hip_runtime.h>
#include <hip/hip_bf16.h>

#define EPSF 1e-8f
#define GAINF 0.014731391274719739f   // 1/sqrt(512*9)

typedef __attribute__((ext_vector_type(8))) __bf16 bf16x8;
typedef __attribute__((ext_vector_type(16))) float f32x16;

// async 16B global->LDS DMA; HW dest = wave-uniform base + lane*16
#define GLOAD_LDS16(gp, lp) __builtin_amdgcn_global_load_lds( \
    (const __attribute__((address_space(1))) unsigned int*)(gp), \
    (__attribute__((address_space(3))) unsigned int*)(lp), 16, 0, 0)

static __device__ __forceinline__ unsigned pkbf(float a, float b) {
  unsigned ua = __bfloat16_as_ushort(__float2bfloat16(a));
  unsigned ub = __bfloat16_as_ushort(__float2bfloat16(b));
  return ua | (ub << 16);
}

// ---------------- K1: pack_x (+border) and prep_w ----------------------------
// xs:  [b][cb16][site1156][32ch] bf16 ; wbf: [t9][cb16][o512][32ch] bf16
__global__ void k_prep(const float* __restrict__ x, const float* __restrict__ style,
                       const float* __restrict__ w, float* __restrict__ S,
                       __hip_bfloat16* __restrict__ wbf, __hip_bfloat16* __restrict__ xs) {
  int blk = blockIdx.x, tid = threadIdx.x;
  if (blk < 1024) {
    // pack: block = (b, cb, quarter): 32ch x 256px, contiguous 1KB-run reads
    __shared__ float lt[256 * 33];
    int b = blk >> 6, cb = (blk >> 2) & 15, q = blk & 3;
    int c = tid >> 3, i8 = tid & 7;
    float st = style[b * 512 + cb * 32 + c];
    const float4* xp = reinterpret_cast<const float4*>(
        x + ((size_t)(b * 512 + cb * 32 + c) * 1024 + q * 256 + i8 * 32));
    float4 v[8];
#pragma unroll
    for (int j = 0; j < 8; ++j) v[j] = xp[j];
    int swz = (c + 4 * i8) & 31;  // 2-way max on store (free)
#pragma unroll
    for (int j = 0; j < 8; ++j) {
      int p = i8 * 32 + j * 4;
      lt[(p + 0) * 33 + swz] = v[j].x * st;
      lt[(p + 1) * 33 + swz] = v[j].y * st;
      lt[(p + 2) * 33 + swz] = v[j].z * st;
      lt[(p + 3) * 33 + swz] = v[j].w * st;
    }
    __syncthreads();
    int p = tid;                       // px-local 0..255
    int pq = q * 256 + p;
    int y = pq >> 5, xx = pq & 31;
    int site = (y + 1) * 34 + (xx + 1);
    __hip_bfloat16* dst = xs + ((size_t)(b * 16 + cb) * 1156 + site) * 32;
    int rs = 4 * (p >> 5);
#pragma unroll
    for (int k = 0; k < 4; ++k) {
      uint4 ov;
      ov.x = pkbf(lt[p * 33 + ((8 * k + 0 + rs) & 31)], lt[p * 33 + ((8 * k + 1 + rs) & 31)]);
      ov.y = pkbf(lt[p * 33 + ((8 * k + 2 + rs) & 31)], lt[p * 33 + ((8 * k + 3 + rs) & 31)]);
      ov.z = pkbf(lt[p * 33 + ((8 * k + 4 + rs) & 31)], lt[p * 33 + ((8 * k + 5 + rs) & 31)]);
      ov.w = pkbf(lt[p * 33 + ((8 * k + 6 + rs) & 31)], lt[p * 33 + ((8 * k + 7 + rs) & 31)]);
      reinterpret_cast<uint4*>(dst)[k] = ov;
    }
    // border zero: 33 of 132 sites per quarter (disjoint from interior writes)
    if (tid < 33) {
      int sbi = q * 33 + tid;
      if (sbi < 132) {
        int yp, xp2;
        if (sbi < 34) { yp = 0; xp2 = sbi; }
        else if (sbi < 68) { yp = 33; xp2 = sbi - 34; }
        else { int t2 = sbi - 68; yp = 1 + (t2 >> 1); xp2 = (t2 & 1) * 33; }
        uint4 z = {0u, 0u, 0u, 0u};
        uint4* zp = reinterpret_cast<uint4*>(
            xs + ((size_t)(b * 16 + cb) * 1156 + yp * 34 + xp2) * 32);
#pragma unroll
        for (int k = 0; k < 4; ++k) zp[k] = z;
      }
    }
  } else {
    // weight -> bf16 [t][cb][o][32] + S[o,i] = sum_t w^2
    int idx = (blk - 1024) * 256 + tid;  // o*512 + i, 262144 total
    int o = idx >> 9, i = idx & 511;
    const float* p = w + (size_t)idx * 9;
    float s = 0.f;
#pragma unroll
    for (int t = 0; t < 9; ++t) {
      float v = p[t];
      s += v * v;
      wbf[(size_t)(t * 16 + (i >> 5)) * 16384 + o * 32 + (i & 31)] = __float2bfloat16(v);
    }
    S[idx] = s;
  }
}

// ---------------- K2: esc[b,o] = GAIN * rsqrt(GAIN^2 * sum_i style^2 S + eps)
__global__ void k_sigma(const float* __restrict__ style, const float* __restrict__ S,
                        float* __restrict__ esc) {
  __shared__ float s2[8192];
  __shared__ float red[4][16];
  int tid = threadIdx.x, o = blockIdx.x;
  for (int idx = tid; idx < 8192; idx += 256) {
    float v = style[idx];
    s2[idx] = v * v;
  }
  __syncthreads();
  float acc[16];
#pragma unroll
  for (int b = 0; b < 16; ++b) acc[b] = 0.f;
  for (int i = tid; i < 512; i += 256) {
    float s = S[o * 512 + i];
#pragma unroll
    for (int b = 0; b < 16; ++b) acc[b] += s2[b * 512 + i] * s;
  }
#pragma unroll
  for (int b = 0; b < 16; ++b)
#pragma unroll
    for (int off = 32; off; off >>= 1) acc[b] += __shfl_down(acc[b], off);
  int lane = tid & 63, wv = tid >> 6;
  if (lane == 0)
#pragma unroll
    for (int b = 0; b < 16; ++b) red[wv][b] = acc[b];
  __syncthreads();
  if (tid < 16) {
    float s = red[0][tid] + red[1][tid] + red[2][tid] + red[3][tid];
    esc[tid * 512 + o] = GAINF * rsqrtf(s * (GAINF * GAINF) + EPSF);
  }
}

// ---------------- K3: implicit-GEMM conv, 32x32x16 bf16 MFMA -----------------
// Wave tile 64o x 128px. 1024 blocks x 64 thr = 4 blocks/CU.
// Conv-aware B dedup: per (dx,k2) group, 6 row-frags feed 24 MFMAs.
// Group-ahead double-buffered A/B fragments (parity arrays, no copies).
__global__ __launch_bounds__(64, 1) void k_conv(
    const __hip_bfloat16* __restrict__ wbf, const __hip_bfloat16* __restrict__ xs,
    const float* __restrict__ esc, float* __restrict__ out) {
  __shared__ __hip_bfloat16 ldsB[2 * 6528];  // 2 bufs x 204 sites x 32 ch
  int g = blockIdx.x;
  int xcd = g & 7, sb = g >> 3;      // sb 0..127
  int m = sb >> 4;                   // 0..7 (64-o tile); same-m runs share A in L1/L2
  int n = xcd * 16 + (sb & 15);      // n-pinned: each XCD owns 2 images of xs
  int b = n >> 3, nt = n & 7;
  int row0 = nt * 4;                 // padded-row base of the 6-row window
  int lane = threadIdx.x;
  int l31 = lane & 31, lhi = lane >> 5;

  // 816 16B chunks (204 sites x 4); XOR bank-swizzle applied on global side
  int roff[13];
#pragma unroll
  for (int j = 0; j < 13; ++j) {
    int idx = lane + j * 64;
    int site = idx >> 2, q0 = idx & 3;
    int qs = q0 ^ ((site >> 1) & 3);
    roff[j] = site * 32 + qs * 8;
  }
  const size_t slab = ((size_t)(b * 16) * 1156 + row0 * 34) * 32;

#define STAGE(cbv) do { \
    const __hip_bfloat16* _g = xs + slab + (size_t)(cbv) * (1156 * 32); \
    __hip_bfloat16* _l = ldsB + ((cbv) & 1) * 6528 + lane * 8; \
    _Pragma("unroll") \
    for (int _j = 0; _j < 12; ++_j) GLOAD_LDS16(_g + roff[_j], _l + _j * 512); \
    if (lane < 48) GLOAD_LDS16(_g + roff[12], _l + 12 * 512); \
  } while (0)

  const __hip_bfloat16* wlane = wbf + (m * 64 + l31) * 32 + lhi * 8;
  // A-frag (t, cb, k2, ms) at: wlane + (t*16+cb)*16384 + ms*1024 + k2*16
#define LOADA(dst, cbv, dxv, k2v) do { \
    _Pragma("unroll") \
    for (int _dy = 0; _dy < 3; ++_dy) \
      _Pragma("unroll") \
      for (int _ms = 0; _ms < 2; ++_ms) \
        dst[_dy * 2 + _ms] = *reinterpret_cast<const bf16x8*>( \
            wlane + (size_t)((3 * _dy + (dxv)) * 16 + (cbv)) * 16384 + _ms * 1024 + (k2v) * 16); \
  } while (0)

  // B row-frags r=0..5 for (dx, k2): site = r*34 + l31 + dx
#define LOADB(dst, bufv, dxv, k2v) do { \
    _Pragma("unroll") \
    for (int _r = 0; _r < 6; ++_r) { \
      int _s = _r * 34 + l31 + (dxv); \
      int _c = (((k2v) << 1) | lhi) ^ ((_s >> 1) & 3); \
      dst[_r] = *reinterpret_cast<const bf16x8*>(&ldsB[(bufv) + (_s * 4 + _c) * 8]); \
    } \
  } while (0)

  f32x16 acc[2][4];
#pragma unroll
  for (int i = 0; i < 2; ++i)
#pragma unroll
    for (int j = 0; j < 4; ++j)
#pragma unroll
      for (int e = 0; e < 16; ++e) acc[i][j][e] = 0.f;

  bf16x8 aA[2][6], bB[2][6];  // parity-double-buffered fragment sets
  STAGE(0);

  for (int cb = 0; cb < 16; ++cb) {
    __syncthreads();               // buffer(cb) DMA (issued last iter) now ready
    if (cb < 15) STAGE(cb + 1);    // 13 DMAs into other buffer, in flight all cb
    int buf = (cb & 1) * 6528;
    LOADB(bB[0], buf, 0, 0);
    LOADA(aA[0], cb, 0, 0);
#pragma unroll
    for (int gg = 0; gg < 6; ++gg) {     // group = (dx = gg>>1, k2 = gg&1)
      const int p = gg & 1;
      if (gg < 5) {                      // prefetch next group: 6 ds + 6 glb
        LOADB(bB[(gg + 1) & 1], buf, (gg + 1) >> 1, (gg + 1) & 1);
        LOADA(aA[(gg + 1) & 1], cb, (gg + 1) >> 1, (gg + 1) & 1);
      }
#pragma unroll
      for (int dy = 0; dy < 3; ++dy)
#pragma unroll
        for (int ns = 0; ns < 4; ++ns) {
          acc[0][ns] = __builtin_amdgcn_mfma_f32_32x32x16_bf16(aA[p][dy * 2 + 0],
                            bB[p][ns + dy], acc[0][ns], 0, 0, 0);
          acc[1][ns] = __builtin_amdgcn_mfma_f32_32x32x16_bf16(aA[p][dy * 2 + 1],
                            bB[p][ns + dy], acc[1][ns], 0, 0, 0);
        }
    }
  }
  // epilogue: C/D layout col=lane&31, row=(reg&3)+8*(reg>>2)+4*(lane>>5)
  int pxb = nt * 128 + l31;
#pragma unroll
  for (int ms = 0; ms < 2; ++ms)
#pragma unroll
    for (int reg = 0; reg < 16; ++reg) {
      int o = m * 64 + ms * 32 + (reg & 3) + ((reg >> 2) << 3) + (lhi << 2);
      float e = esc[(b << 9) + o];
      float* op = out + ((size_t)((b << 9) + o) << 10) + pxb;
#pragma unroll
      for (int ns = 0; ns < 4; ++ns)
        op[ns * 32] = acc[ms][ns][reg] * e;
    }
#undef STAGE
#undef LOADA
#undef LOADB
}

extern "C" void kernel_launch(void* const* d_in, const int* in_sizes, int n_in,
                              void* d_out, int out_size, void* d_ws, size_t ws_size,
                              hipStream_t stream) {
  const float* x = (const float*)d_in[0];      // [16,512,32,32]
  const float* style = (const float*)d_in[1];  // [16,512]
  const float* w = (const float*)d_in[2];      // [512,512,3,3]
  float* out = (float*)d_out;                  // [16,512,32,32]
  char* ws = (char*)d_ws;
  __hip_bfloat16* wbf = (__hip_bfloat16*)(ws);            // 4,718,592 B
  __hip_bfloat16* xs  = (__hip_bfloat16*)(ws + 4718592);  // 18,939,904 B
  float* S   = (float*)(ws + 23658496);                   // 1,048,576 B
  float* esc = (float*)(ws + 24707072);                   // 32,768 B

  hipLaunchKernelGGL(k_prep, dim3(2048), dim3(256), 0, stream, x, style, w, S, wbf, xs);
  hipLaunchKernelGGL(k_sigma, dim3(512), dim3(256), 0, stream, style, S, esc);
  hipLaunchKernelGGL(k_conv, dim3(1024), dim3(64), 0, stream, wbf, xs, esc, out);
}